// Round 2
// baseline (344.998 us; speedup 1.0000x reference)
//
#include <hip/hip_runtime.h>

typedef __attribute__((ext_vector_type(8))) short short8;
typedef __attribute__((ext_vector_type(4))) float f32x4;

static __device__ __forceinline__ unsigned short f2bf(float f) {
  union { float f; unsigned int u; } v; v.f = f;
  unsigned int r = v.u + 0x7FFFu + ((v.u >> 16) & 1u);
  return (unsigned short)(r >> 16);
}
static __device__ __forceinline__ unsigned int pack2(float a, float b) {
  return (unsigned int)f2bf(a) | ((unsigned int)f2bf(b) << 16);
}

#define XP 136   // X/O row pitch (shorts): 68 dwords -> 4-bank row skew, 2-way max
#define VP 72
#define PP 72
#define X_OFF 0
#define Q_OFF (X_OFF + 64 * XP)
#define K_OFF (Q_OFF + 64 * XP)
#define V_OFF (K_OFF + 64 * XP)
#define P_OFF (V_OFF + 128 * VP)
#define TBL_OFF (P_OFF + 4 * 64 * PP)
#define LDS_SHORTS (TBL_OFF + 2 * 676)

// ---------------- prep: convert weights to bf16 ----------------
__global__ __launch_bounds__(256) void k_prep(const float* __restrict__ wq,
    const float* __restrict__ wp, unsigned short* __restrict__ dq,
    unsigned short* __restrict__ dp) {
  int i = blockIdx.x * 256 + threadIdx.x;
  if (i < 384 * 128) dq[i] = f2bf(wq[i]);
  if (i < 128 * 128) dp[i] = f2bf(wp[i]);
}

static __device__ __forceinline__ int reg3(int y) { return y < 49 ? 0 : (y < 53 ? 1 : 2); }

// ---------------- fully fused: gather -> QKV -> attn -> proj -> scatter ----------------
// one block per window (4096 blocks), 256 threads (4 waves; wave = head = N-quarter)
__global__ __launch_bounds__(256, 1) void k_fused(const float* __restrict__ x,
    const unsigned short* __restrict__ Wq, const float* __restrict__ qb,
    const unsigned short* __restrict__ Wp, const float* __restrict__ pb,
    const float* __restrict__ table, float* __restrict__ out) {
  __shared__ __align__(16) unsigned short lds[LDS_SHORTS];
  const int tid = threadIdx.x;
  const int win = blockIdx.x;
  const int b = win >> 6, wl = win & 63;
  const int wh = wl >> 3, ww = wl & 7;

  // zero P region (pad rows 49..63 are read by PV A-operand; must be finite)
  for (int i = tid; i < 4 * 64 * PP; i += 256) lds[P_OFF + i] = 0;
  // stage rel-pos table (676 floats)
  float* tbl = (float*)&lds[TBL_OFF];
  for (int i = tid; i < 676; i += 256) tbl[i] = table[i];

  // gather shifted x tile -> bf16 LDS; zero pad rows 49..63
  {
    const int r = tid >> 2, qt = tid & 3;
    unsigned short* dst = lds + X_OFF + r * XP + qt * 32;
    if (r < 49) {
      const int th = r / 7, tw = r - th * 7;
      int sh = wh * 7 + th + 3; if (sh >= 56) sh -= 56;
      int sw = ww * 7 + tw + 3; if (sw >= 56) sw -= 56;
      const float4* src = (const float4*)(x + (((size_t)(b * 56 + sh)) * 56 + sw) * 128 + qt * 32);
#pragma unroll
      for (int i = 0; i < 4; ++i) {
        float4 fa = src[2 * i], fb = src[2 * i + 1];
        uint4 u;
        u.x = pack2(fa.x, fa.y); u.y = pack2(fa.z, fa.w);
        u.z = pack2(fb.x, fb.y); u.w = pack2(fb.z, fb.w);
        *(uint4*)(dst + i * 8) = u;
      }
    } else {
      const uint4 z = {0u, 0u, 0u, 0u};
#pragma unroll
      for (int i = 0; i < 4; ++i) *(uint4*)(dst + i * 8) = z;
    }
  }
  __syncthreads();

  const int wv = tid >> 6, ln = tid & 63;
  const int l15 = ln & 15, l4 = ln >> 4;
  const f32x4 z4 = {0.f, 0.f, 0.f, 0.f};

  // ---- QKV GEMM: [64x128] @ [128x384]^T, wave wv covers n in [96wv, 96wv+96) ----
  f32x4 acc[4][6];
#pragma unroll
  for (int mt = 0; mt < 4; ++mt)
#pragma unroll
    for (int nt = 0; nt < 6; ++nt) acc[mt][nt] = z4;
#pragma unroll
  for (int ks = 0; ks < 4; ++ks) {
    short8 af[4], bf[6];
#pragma unroll
    for (int mt = 0; mt < 4; ++mt)
      af[mt] = *(const short8*)&lds[X_OFF + (mt * 16 + l15) * XP + ks * 32 + l4 * 8];
#pragma unroll
    for (int nt = 0; nt < 6; ++nt)
      bf[nt] = *(const short8*)&Wq[(size_t)(wv * 96 + nt * 16 + l15) * 128 + ks * 32 + l4 * 8];
#pragma unroll
    for (int mt = 0; mt < 4; ++mt)
#pragma unroll
      for (int nt = 0; nt < 6; ++nt)
        acc[mt][nt] = __builtin_amdgcn_mfma_f32_16x16x32_bf16(af[mt], bf[nt], acc[mt][nt], 0, 0, 0);
  }
  // epilogue: bias, q-scale, route to Q/K/V LDS regions
#pragma unroll
  for (int nt = 0; nt < 6; ++nt) {
    const int n = wv * 96 + nt * 16 + l15;
    const float bb = qb[n];
#pragma unroll
    for (int mt = 0; mt < 4; ++mt)
#pragma unroll
      for (int r = 0; r < 4; ++r) {
        const int t = mt * 16 + l4 * 4 + r;
        const float v = acc[mt][nt][r] + bb;
        if (n < 128)      lds[Q_OFF + t * XP + n] = f2bf(v * 0.17677669529663687f);
        else if (n < 256) lds[K_OFF + t * XP + (n - 128)] = f2bf(v);
        else              lds[V_OFF + (n - 256) * VP + t] = f2bf(v);
      }
  }
  __syncthreads();

  // ---- attention, head h = wv ----
  const int h = wv;
  f32x4 s[4][4];
#pragma unroll
  for (int mt = 0; mt < 4; ++mt)
#pragma unroll
    for (int nt = 0; nt < 4; ++nt) s[mt][nt] = z4;
  {
    short8 af[4], bq[4];
#pragma unroll
    for (int mt = 0; mt < 4; ++mt)
      af[mt] = *(const short8*)&lds[Q_OFF + (mt * 16 + l15) * XP + h * 32 + l4 * 8];
#pragma unroll
    for (int nt = 0; nt < 4; ++nt)
      bq[nt] = *(const short8*)&lds[K_OFF + (nt * 16 + l15) * XP + h * 32 + l4 * 8];
#pragma unroll
    for (int mt = 0; mt < 4; ++mt)
#pragma unroll
      for (int nt = 0; nt < 4; ++nt)
        s[mt][nt] = __builtin_amdgcn_mfma_f32_16x16x32_bf16(af[mt], bq[nt], s[mt][nt], 0, 0, 0);
  }
  // softmax (bias + shift-mask), P -> LDS bf16
  unsigned short* Ph = lds + P_OFF + h * 64 * PP;
  int jh_[4], jw_[4], jreg[4], jj[4];
#pragma unroll
  for (int nt = 0; nt < 4; ++nt) {
    const int j = nt * 16 + l15;
    jj[nt] = j;
    const int jh = j / 7, jw = j - jh * 7;
    jh_[nt] = jh; jw_[nt] = jw;
    jreg[nt] = 3 * reg3(wh * 7 + jh) + reg3(ww * 7 + jw);
  }
#pragma unroll
  for (int mt = 0; mt < 4; ++mt) {
#pragma unroll
    for (int r = 0; r < 4; ++r) {
      const int i = mt * 16 + l4 * 4 + r;
      const int ih = i / 7, iw = i - ih * 7;
      const int ireg = 3 * reg3(wh * 7 + ih) + reg3(ww * 7 + iw);
      float e[4];
      float mx = -1e30f;
#pragma unroll
      for (int nt = 0; nt < 4; ++nt) {
        int didx = (ih - jh_[nt] + 6) * 13 + (iw - jw_[nt] + 6);
        didx = didx < 0 ? 0 : (didx > 168 ? 168 : didx);
        float v = s[mt][nt][r] + tbl[didx * 4 + h];
        if (ireg != jreg[nt]) v -= 100.0f;
        if (jj[nt] >= 49) v = -1e30f;
        e[nt] = v;
        mx = fmaxf(mx, v);
      }
#pragma unroll
      for (int off = 1; off < 16; off <<= 1) mx = fmaxf(mx, __shfl_xor(mx, off, 16));
      float sum = 0.0f;
#pragma unroll
      for (int nt = 0; nt < 4; ++nt) {
        float ev = (e[nt] > -1e29f) ? __expf(e[nt] - mx) : 0.0f;
        e[nt] = ev; sum += ev;
      }
#pragma unroll
      for (int off = 1; off < 16; off <<= 1) sum += __shfl_xor(sum, off, 16);
      const float inv = 1.0f / sum;
      if (i < 49) {
#pragma unroll
        for (int nt = 0; nt < 4; ++nt)
          Ph[i * PP + jj[nt]] = f2bf(e[nt] * inv);
      }
    }
  }
  // PV: O[64x32] = P[64x64] @ V[64x32]
  f32x4 o[4][2];
#pragma unroll
  for (int mt = 0; mt < 4; ++mt)
#pragma unroll
    for (int dt = 0; dt < 2; ++dt) o[mt][dt] = z4;
#pragma unroll
  for (int ks = 0; ks < 2; ++ks) {
    short8 pa[4], vb[2];
#pragma unroll
    for (int mt = 0; mt < 4; ++mt)
      pa[mt] = *(const short8*)&Ph[(mt * 16 + l15) * PP + ks * 32 + l4 * 8];
#pragma unroll
    for (int dt = 0; dt < 2; ++dt)
      vb[dt] = *(const short8*)&lds[V_OFF + (h * 32 + dt * 16 + l15) * VP + ks * 32 + l4 * 8];
#pragma unroll
    for (int mt = 0; mt < 4; ++mt)
#pragma unroll
      for (int dt = 0; dt < 2; ++dt)
        o[mt][dt] = __builtin_amdgcn_mfma_f32_16x16x32_bf16(pa[mt], vb[dt], o[mt][dt], 0, 0, 0);
  }
  // stage O into X region (X dead after QKV; all waves passed that barrier)
#pragma unroll
  for (int mt = 0; mt < 4; ++mt)
#pragma unroll
    for (int dt = 0; dt < 2; ++dt)
#pragma unroll
      for (int r = 0; r < 4; ++r)
        lds[X_OFF + (mt * 16 + l4 * 4 + r) * XP + h * 32 + dt * 16 + l15] = f2bf(o[mt][dt][r]);
  __syncthreads();

  // ---- proj GEMM: [64x128] @ [128x128]^T, wave wv covers n in [32wv, 32wv+32) ----
  f32x4 c2[4][2];
#pragma unroll
  for (int mt = 0; mt < 4; ++mt)
#pragma unroll
    for (int nt = 0; nt < 2; ++nt) c2[mt][nt] = z4;
#pragma unroll
  for (int ks = 0; ks < 4; ++ks) {
    short8 af[4], bp[2];
#pragma unroll
    for (int mt = 0; mt < 4; ++mt)
      af[mt] = *(const short8*)&lds[X_OFF + (mt * 16 + l15) * XP + ks * 32 + l4 * 8];
#pragma unroll
    for (int nt = 0; nt < 2; ++nt)
      bp[nt] = *(const short8*)&Wp[(size_t)(wv * 32 + nt * 16 + l15) * 128 + ks * 32 + l4 * 8];
#pragma unroll
    for (int mt = 0; mt < 4; ++mt)
#pragma unroll
      for (int nt = 0; nt < 2; ++nt)
        c2[mt][nt] = __builtin_amdgcn_mfma_f32_16x16x32_bf16(af[mt], bp[nt], c2[mt][nt], 0, 0, 0);
  }
  // scatter with reverse shift
#pragma unroll
  for (int mt = 0; mt < 4; ++mt) {
#pragma unroll
    for (int r = 0; r < 4; ++r) {
      const int t = mt * 16 + l4 * 4 + r;
      if (t < 49) {
        const int th = t / 7, tw = t - th * 7;
        int y = wh * 7 + th + 3; if (y >= 56) y -= 56;
        int xx = ww * 7 + tw + 3; if (xx >= 56) xx -= 56;
        float* dstp = out + (((size_t)(b * 56 + y)) * 56 + xx) * 128;
#pragma unroll
        for (int nt = 0; nt < 2; ++nt) {
          const int n = wv * 32 + nt * 16 + l15;
          dstp[n] = c2[mt][nt][r] + pb[n];
        }
      }
    }
  }
}

extern "C" void kernel_launch(void* const* d_in, const int* in_sizes, int n_in,
                              void* d_out, int out_size, void* d_ws, size_t ws_size,
                              hipStream_t stream) {
  const float* x     = (const float*)d_in[0];
  const float* qkvw  = (const float*)d_in[1];
  const float* qkvb  = (const float*)d_in[2];
  const float* projw = (const float*)d_in[3];
  const float* projb = (const float*)d_in[4];
  const float* table = (const float*)d_in[5];
  float* out = (float*)d_out;
  char* ws = (char*)d_ws;
  unsigned short* Wq = (unsigned short*)ws;            // 98304 B
  unsigned short* Wp = (unsigned short*)(ws + 98304);  // 32768 B

  k_prep<<<dim3(192), dim3(256), 0, stream>>>(qkvw, projw, Wq, Wp);
  k_fused<<<dim3(4096), dim3(256), 0, stream>>>(x, Wq, qkvb, Wp, projb, table, out);
}

// Round 3
// 164.002 us; speedup vs baseline: 2.1036x; 2.1036x over previous
//
#include <hip/hip_runtime.h>

typedef __attribute__((ext_vector_type(8))) short short8;
typedef __attribute__((ext_vector_type(4))) float f32x4;

static __device__ __forceinline__ unsigned short f2bf(float f) {
  union { float f; unsigned int u; } v; v.f = f;
  unsigned int r = v.u + 0x7FFFu + ((v.u >> 16) & 1u);
  return (unsigned short)(r >> 16);
}
static __device__ __forceinline__ unsigned int pack2(float a, float b) {
  return (unsigned int)f2bf(a) | ((unsigned int)f2bf(b) << 16);
}

// per-wave LDS region (shorts): K/O [64][40], V^T [32][72], P/Qs [64][40], tbl 169 f32
#define KO 0
#define VO 2560
#define PO 4864
#define TO 7424
#define WSTRIDE 7776   // shorts; 15552 B per wave, 16B-aligned

// ---------------- prep: convert weights to bf16 ----------------
__global__ __launch_bounds__(256) void k_prep(const float* __restrict__ wq,
    const float* __restrict__ wp, unsigned short* __restrict__ dq,
    unsigned short* __restrict__ dp) {
  int i = blockIdx.x * 256 + threadIdx.x;
  if (i < 384 * 128) dq[i] = f2bf(wq[i]);
  if (i < 128 * 128) dp[i] = f2bf(wp[i]);
}

static __device__ __forceinline__ int reg3(int y) { return y < 49 ? 0 : (y < 53 ? 1 : 2); }

// one block per window (4096), 4 waves, wave == head, barrier-free until proj
__global__ __launch_bounds__(256, 2) void k_fused(const float* __restrict__ x,
    const unsigned short* __restrict__ Wq, const float* __restrict__ qb,
    const unsigned short* __restrict__ Wp, const float* __restrict__ pb,
    const float* __restrict__ table, float* __restrict__ out) {
  __shared__ __align__(16) unsigned short lds[4 * WSTRIDE];
  const int tid = threadIdx.x;
  const int win = blockIdx.x;
  const int b = win >> 6, wl = win & 63;
  const int wh = wl >> 3, ww = wl & 7;
  const int wv = tid >> 6, ln = tid & 63;
  const int l15 = ln & 15, l4 = ln >> 4;
  unsigned short* W = lds + wv * WSTRIDE;
  float* tblw = (float*)&W[TO];

  // stage own head's rel-pos bias slice (169 floats)
  for (int i = ln; i < 169; i += 64) tblw[i] = table[i * 4 + wv];

  // A-row pointers for the QKV GEMM (shifted gather), rows t = mt*16 + l15
  const float* rp[4];
  int vld[4];
#pragma unroll
  for (int mt = 0; mt < 4; ++mt) {
    const int t = mt * 16 + l15;
    vld[mt] = (t < 49);
    int th = t / 7, tw = t - th * 7;
    int sh = wh * 7 + th + 3; if (sh >= 56) sh -= 56;
    int sw = ww * 7 + tw + 3; if (sw >= 56) sw -= 56;
    rp[mt] = x + (((size_t)(b * 56 + (vld[mt] ? sh : 0))) * 56 + (vld[mt] ? sw : 0)) * 128;
  }
  // B rows: wave wv owns n in {32wv..}+ {128+32wv..} + {256+32wv..}
  int nrow[6];
#pragma unroll
  for (int j = 0; j < 6; ++j) {
    const int grp = j >> 1, sub = j & 1;
    nrow[j] = grp * 128 + wv * 32 + sub * 16 + l15;
  }

  const f32x4 z4 = {0.f, 0.f, 0.f, 0.f};
  // ---- QKV GEMM: per-wave 64x96 slice ----
  f32x4 acc[4][6];
#pragma unroll
  for (int mt = 0; mt < 4; ++mt)
#pragma unroll
    for (int j = 0; j < 6; ++j) acc[mt][j] = z4;
#pragma unroll
  for (int ks = 0; ks < 4; ++ks) {
    short8 af[4], bf[6];
#pragma unroll
    for (int mt = 0; mt < 4; ++mt) {
      if (vld[mt]) {
        const float4* p = (const float4*)(rp[mt] + ks * 32 + l4 * 8);
        float4 fa = p[0], fb = p[1];
        uint4 u;
        u.x = pack2(fa.x, fa.y); u.y = pack2(fa.z, fa.w);
        u.z = pack2(fb.x, fb.y); u.w = pack2(fb.z, fb.w);
        af[mt] = *(short8*)&u;
      } else {
        const uint4 u = {0u, 0u, 0u, 0u};
        af[mt] = *(short8*)&u;
      }
    }
#pragma unroll
    for (int j = 0; j < 6; ++j)
      bf[j] = *(const short8*)&Wq[(size_t)nrow[j] * 128 + ks * 32 + l4 * 8];
#pragma unroll
    for (int mt = 0; mt < 4; ++mt)
#pragma unroll
      for (int j = 0; j < 6; ++j)
        acc[mt][j] = __builtin_amdgcn_mfma_f32_16x16x32_bf16(af[mt], bf[j], acc[mt][j], 0, 0, 0);
  }
  // epilogue: bias (+q scale), route to own-wave LDS: Q->PO (as [t][d]), K->KO [t][d], V->VO [d][t]
#pragma unroll
  for (int j = 0; j < 6; ++j) {
    const float bb = qb[nrow[j]];
    const int grp = j >> 1, sub = j & 1;
#pragma unroll
    for (int mt = 0; mt < 4; ++mt)
#pragma unroll
      for (int r = 0; r < 4; ++r) {
        const int t = mt * 16 + l4 * 4 + r;
        const float v = acc[mt][j][r] + bb;
        if (grp == 0)      W[PO + t * 40 + sub * 16 + l15] = f2bf(v * 0.17677669529663687f);
        else if (grp == 1) W[KO + t * 40 + sub * 16 + l15] = f2bf(v);
        else               W[VO + (sub * 16 + l15) * 72 + t] = f2bf(v);
      }
  }
  // ---- QK^T (own head) ----
  short8 qf[4], kf[4];
#pragma unroll
  for (int mt = 0; mt < 4; ++mt)
    qf[mt] = *(const short8*)&W[PO + (mt * 16 + l15) * 40 + l4 * 8];
#pragma unroll
  for (int nt = 0; nt < 4; ++nt)
    kf[nt] = *(const short8*)&W[KO + (nt * 16 + l15) * 40 + l4 * 8];
  f32x4 s[4][4];
#pragma unroll
  for (int mt = 0; mt < 4; ++mt)
#pragma unroll
    for (int nt = 0; nt < 4; ++nt) s[mt][nt] = z4;
#pragma unroll
  for (int mt = 0; mt < 4; ++mt)
#pragma unroll
    for (int nt = 0; nt < 4; ++nt)
      s[mt][nt] = __builtin_amdgcn_mfma_f32_16x16x32_bf16(qf[mt], kf[nt], s[mt][nt], 0, 0, 0);

  // ---- softmax (bias + shift mask); P cols 0..31 -> LDS, cols 32..63 stashed ----
  int jh_[4], jw_[4], jreg[4], jj[4];
#pragma unroll
  for (int nt = 0; nt < 4; ++nt) {
    const int j = nt * 16 + l15;
    jj[nt] = j;
    const int jh = j / 7, jw = j - jh * 7;
    jh_[nt] = jh; jw_[nt] = jw;
    jreg[nt] = 3 * reg3(wh * 7 + jh) + reg3(ww * 7 + jw);
  }
  float est2[16], est3[16];
#pragma unroll
  for (int mt = 0; mt < 4; ++mt) {
#pragma unroll
    for (int r = 0; r < 4; ++r) {
      const int i = mt * 16 + l4 * 4 + r;
      const int ih = i / 7, iw = i - ih * 7;
      const int ireg = 3 * reg3(wh * 7 + ih) + reg3(ww * 7 + iw);
      float e[4];
      float mx = -1e30f;
#pragma unroll
      for (int nt = 0; nt < 4; ++nt) {
        int didx = (ih - jh_[nt] + 6) * 13 + (iw - jw_[nt] + 6);
        didx = didx < 0 ? 0 : (didx > 168 ? 168 : didx);
        float v = s[mt][nt][r] + tblw[didx];
        if (ireg != jreg[nt]) v -= 100.0f;
        if (jj[nt] >= 49) v = -1e30f;
        e[nt] = v;
        mx = fmaxf(mx, v);
      }
#pragma unroll
      for (int off = 1; off < 16; off <<= 1) mx = fmaxf(mx, __shfl_xor(mx, off, 16));
      float sum = 0.0f;
#pragma unroll
      for (int nt = 0; nt < 4; ++nt) {
        float ev = (e[nt] > -1e29f) ? __expf(e[nt] - mx) : 0.0f;
        e[nt] = ev; sum += ev;
      }
#pragma unroll
      for (int off = 1; off < 16; off <<= 1) sum += __shfl_xor(sum, off, 16);
      const float inv = 1.0f / sum;
      if (i < 49) {
        W[PO + i * 40 + l15]      = f2bf(e[0] * inv);
        W[PO + i * 40 + 16 + l15] = f2bf(e[1] * inv);
      }
      est2[mt * 4 + r] = e[2] * inv;
      est3[mt * 4 + r] = e[3] * inv;
    }
  }
  // ---- PV ks=0 (k=0..31) ----
  f32x4 o[4][2];
#pragma unroll
  for (int mt = 0; mt < 4; ++mt)
#pragma unroll
    for (int dt = 0; dt < 2; ++dt) o[mt][dt] = z4;
  {
    short8 pa[4], vb[2];
#pragma unroll
    for (int mt = 0; mt < 4; ++mt)
      pa[mt] = *(const short8*)&W[PO + (mt * 16 + l15) * 40 + l4 * 8];
#pragma unroll
    for (int dt = 0; dt < 2; ++dt)
      vb[dt] = *(const short8*)&W[VO + (dt * 16 + l15) * 72 + l4 * 8];
#pragma unroll
    for (int mt = 0; mt < 4; ++mt)
#pragma unroll
      for (int dt = 0; dt < 2; ++dt)
        o[mt][dt] = __builtin_amdgcn_mfma_f32_16x16x32_bf16(pa[mt], vb[dt], o[mt][dt], 0, 0, 0);
  }
  // write P cols 32..63 (same slots), PV ks=1
#pragma unroll
  for (int mt = 0; mt < 4; ++mt)
#pragma unroll
    for (int r = 0; r < 4; ++r) {
      const int i = mt * 16 + l4 * 4 + r;
      if (i < 49) {
        W[PO + i * 40 + l15]      = f2bf(est2[mt * 4 + r]);
        W[PO + i * 40 + 16 + l15] = f2bf(est3[mt * 4 + r]);
      }
    }
  {
    short8 pa[4], vb[2];
#pragma unroll
    for (int mt = 0; mt < 4; ++mt)
      pa[mt] = *(const short8*)&W[PO + (mt * 16 + l15) * 40 + l4 * 8];
#pragma unroll
    for (int dt = 0; dt < 2; ++dt)
      vb[dt] = *(const short8*)&W[VO + (dt * 16 + l15) * 72 + 32 + l4 * 8];
#pragma unroll
    for (int mt = 0; mt < 4; ++mt)
#pragma unroll
      for (int dt = 0; dt < 2; ++dt)
        o[mt][dt] = __builtin_amdgcn_mfma_f32_16x16x32_bf16(pa[mt], vb[dt], o[mt][dt], 0, 0, 0);
  }
  // stage O_h into own K buffer as [t][d(32)+pad]
#pragma unroll
  for (int mt = 0; mt < 4; ++mt)
#pragma unroll
    for (int dt = 0; dt < 2; ++dt)
#pragma unroll
      for (int r = 0; r < 4; ++r)
        W[KO + (mt * 16 + l4 * 4 + r) * 40 + dt * 16 + l15] = f2bf(o[mt][dt][r]);

  __syncthreads();

  // ---- proj: A k-slice ks lives in wave-ks's K buffer ----
  f32x4 c2[4][2];
#pragma unroll
  for (int mt = 0; mt < 4; ++mt)
#pragma unroll
    for (int nt = 0; nt < 2; ++nt) c2[mt][nt] = z4;
#pragma unroll
  for (int ks = 0; ks < 4; ++ks) {
    short8 af[4], bp[2];
#pragma unroll
    for (int mt = 0; mt < 4; ++mt)
      af[mt] = *(const short8*)&lds[ks * WSTRIDE + KO + (mt * 16 + l15) * 40 + l4 * 8];
#pragma unroll
    for (int nt = 0; nt < 2; ++nt)
      bp[nt] = *(const short8*)&Wp[(size_t)(wv * 32 + nt * 16 + l15) * 128 + ks * 32 + l4 * 8];
#pragma unroll
    for (int mt = 0; mt < 4; ++mt)
#pragma unroll
      for (int nt = 0; nt < 2; ++nt)
        c2[mt][nt] = __builtin_amdgcn_mfma_f32_16x16x32_bf16(af[mt], bp[nt], c2[mt][nt], 0, 0, 0);
  }
  // scatter with reverse shift
#pragma unroll
  for (int mt = 0; mt < 4; ++mt) {
#pragma unroll
    for (int r = 0; r < 4; ++r) {
      const int t = mt * 16 + l4 * 4 + r;
      if (t < 49) {
        const int th = t / 7, tw = t - th * 7;
        int y = wh * 7 + th + 3; if (y >= 56) y -= 56;
        int xx = ww * 7 + tw + 3; if (xx >= 56) xx -= 56;
        float* dstp = out + (((size_t)(b * 56 + y)) * 56 + xx) * 128;
#pragma unroll
        for (int nt = 0; nt < 2; ++nt) {
          const int n = wv * 32 + nt * 16 + l15;
          dstp[n] = c2[mt][nt][r] + pb[n];
        }
      }
    }
  }
}

extern "C" void kernel_launch(void* const* d_in, const int* in_sizes, int n_in,
                              void* d_out, int out_size, void* d_ws, size_t ws_size,
                              hipStream_t stream) {
  const float* x     = (const float*)d_in[0];
  const float* qkvw  = (const float*)d_in[1];
  const float* qkvb  = (const float*)d_in[2];
  const float* projw = (const float*)d_in[3];
  const float* projb = (const float*)d_in[4];
  const float* table = (const float*)d_in[5];
  float* out = (float*)d_out;
  char* ws = (char*)d_ws;
  unsigned short* Wq = (unsigned short*)ws;            // 98304 B
  unsigned short* Wp = (unsigned short*)(ws + 98304);  // 32768 B

  k_prep<<<dim3(192), dim3(256), 0, stream>>>(qkvw, projw, Wq, Wp);
  k_fused<<<dim3(4096), dim3(256), 0, stream>>>(x, Wq, qkvb, Wp, projb, table, out);
}

// Round 5
// 153.975 us; speedup vs baseline: 2.2406x; 1.0651x over previous
//
#include <hip/hip_runtime.h>

typedef __attribute__((ext_vector_type(8))) short short8;
typedef __attribute__((ext_vector_type(4))) float f32x4;

static __device__ __forceinline__ unsigned short f2bf(float f) {
  union { float f; unsigned int u; } v; v.f = f;
  unsigned int r = v.u + 0x7FFFu + ((v.u >> 16) & 1u);
  return (unsigned short)(r >> 16);
}
static __device__ __forceinline__ unsigned int pack2(float a, float b) {
  return (unsigned int)f2bf(a) | ((unsigned int)f2bf(b) << 16);
}

// per-wave LDS (shorts): Q/P [64][40], K/O [64][40], V^T [32][72], tbl 169 f32
#define QO 0
#define KO 2560
#define VO 5120
#define TO 7424
#define WSTRIDE 7776   // 15552 B per wave

__global__ __launch_bounds__(256) void k_prep(const float* __restrict__ wq,
    const float* __restrict__ wp, unsigned short* __restrict__ dq,
    unsigned short* __restrict__ dp) {
  int i = blockIdx.x * 256 + threadIdx.x;
  if (i < 384 * 128) dq[i] = f2bf(wq[i]);
  if (i < 128 * 128) dp[i] = f2bf(wp[i]);
}

static __device__ __forceinline__ int reg3(int y) { return y < 49 ? 0 : (y < 53 ? 1 : 2); }

// one block per window (4096), 4 waves, wave == head; single barrier before proj
__global__ __launch_bounds__(256, 2) void k_fused(const float* __restrict__ x,
    const unsigned short* __restrict__ Wq, const float* __restrict__ qb,
    const unsigned short* __restrict__ Wp, const float* __restrict__ pb,
    const float* __restrict__ table, float* __restrict__ out) {
  __shared__ __align__(16) unsigned short lds[4 * WSTRIDE];
  const int tid = threadIdx.x;
  const int win = blockIdx.x;
  const int b = win >> 6, wl = win & 63;
  const int wh = wl >> 3, ww = wl & 7;
  const int wv = tid >> 6, ln = tid & 63;
  const int l15 = ln & 15, l4 = ln >> 4;
  unsigned short* W = lds + wv * WSTRIDE;
  float* tblw = (float*)&W[TO];

  for (int i = ln; i < 169; i += 64) tblw[i] = table[i * 4 + wv];

  // A-row pointers (shifted gather); pad rows point at row 0 (finite), zeroed below
  const float* rp[4];
  bool vld[4];
#pragma unroll
  for (int mt = 0; mt < 4; ++mt) {
    const int t = mt * 16 + l15;
    vld[mt] = (t < 49);
    const int tc = vld[mt] ? t : 0;
    const int th = tc / 7, tw = tc - th * 7;
    int sh = wh * 7 + th + 3; if (sh >= 56) sh -= 56;
    int sw = ww * 7 + tw + 3; if (sw >= 56) sw -= 56;
    rp[mt] = x + (((size_t)(b * 56 + sh)) * 56 + sw) * 128;
  }
  int nrow[6];
#pragma unroll
  for (int j = 0; j < 6; ++j)
    nrow[j] = (j >> 1) * 128 + wv * 32 + (j & 1) * 16 + l15;

  const f32x4 z4 = {0.f, 0.f, 0.f, 0.f};
  // ---- QKV: Q,K swapped (lane: t=l15-row, 4 consecutive d); V unswapped ----
  f32x4 aS[4][4], aV[4][2];
#pragma unroll
  for (int mt = 0; mt < 4; ++mt) {
#pragma unroll
    for (int j = 0; j < 4; ++j) aS[mt][j] = z4;
#pragma unroll
    for (int j = 0; j < 2; ++j) aV[mt][j] = z4;
  }
#pragma unroll
  for (int ks = 0; ks < 4; ++ks) {
    short8 af[4], bf[6];
#pragma unroll
    for (int mt = 0; mt < 4; ++mt) {
      const float4* p = (const float4*)(rp[mt] + ks * 32 + l4 * 8);
      float4 fa = p[0], fb = p[1];
      uint4 u;
      u.x = pack2(fa.x, fa.y); u.y = pack2(fa.z, fa.w);
      u.z = pack2(fb.x, fb.y); u.w = pack2(fb.z, fb.w);
      u.x = vld[mt] ? u.x : 0u; u.y = vld[mt] ? u.y : 0u;
      u.z = vld[mt] ? u.z : 0u; u.w = vld[mt] ? u.w : 0u;
      af[mt] = *(short8*)&u;
    }
#pragma unroll
    for (int j = 0; j < 6; ++j)
      bf[j] = *(const short8*)&Wq[(size_t)nrow[j] * 128 + ks * 32 + l4 * 8];
#pragma unroll
    for (int mt = 0; mt < 4; ++mt) {
#pragma unroll
      for (int j = 0; j < 4; ++j)
        aS[mt][j] = __builtin_amdgcn_mfma_f32_16x16x32_bf16(bf[j], af[mt], aS[mt][j], 0, 0, 0);
#pragma unroll
      for (int j = 0; j < 2; ++j)
        aV[mt][j] = __builtin_amdgcn_mfma_f32_16x16x32_bf16(af[mt], bf[4 + j], aV[mt][j], 0, 0, 0);
    }
  }
  // epilogue: packed b64 writes
  {
    const float SC = 0.17677669529663687f;
    const float4 bq0 = *(const float4*)(qb + wv * 32 + 4 * l4);
    const float4 bq1 = *(const float4*)(qb + wv * 32 + 16 + 4 * l4);
    const float4 bk0 = *(const float4*)(qb + 128 + wv * 32 + 4 * l4);
    const float4 bk1 = *(const float4*)(qb + 128 + wv * 32 + 16 + 4 * l4);
    const float bv0 = qb[256 + wv * 32 + l15];
    const float bv1 = qb[256 + wv * 32 + 16 + l15];
#pragma unroll
    for (int mt = 0; mt < 4; ++mt) {
      const int t = mt * 16 + l15;
      uint2 u;
      u.x = pack2((aS[mt][0][0] + bq0.x) * SC, (aS[mt][0][1] + bq0.y) * SC);
      u.y = pack2((aS[mt][0][2] + bq0.z) * SC, (aS[mt][0][3] + bq0.w) * SC);
      *(uint2*)&W[QO + t * 40 + 4 * l4] = u;
      u.x = pack2((aS[mt][1][0] + bq1.x) * SC, (aS[mt][1][1] + bq1.y) * SC);
      u.y = pack2((aS[mt][1][2] + bq1.z) * SC, (aS[mt][1][3] + bq1.w) * SC);
      *(uint2*)&W[QO + t * 40 + 16 + 4 * l4] = u;
      u.x = pack2(aS[mt][2][0] + bk0.x, aS[mt][2][1] + bk0.y);
      u.y = pack2(aS[mt][2][2] + bk0.z, aS[mt][2][3] + bk0.w);
      *(uint2*)&W[KO + t * 40 + 4 * l4] = u;
      u.x = pack2(aS[mt][3][0] + bk1.x, aS[mt][3][1] + bk1.y);
      u.y = pack2(aS[mt][3][2] + bk1.z, aS[mt][3][3] + bk1.w);
      *(uint2*)&W[KO + t * 40 + 16 + 4 * l4] = u;
      u.x = pack2(aV[mt][0][0] + bv0, aV[mt][0][1] + bv0);
      u.y = pack2(aV[mt][0][2] + bv0, aV[mt][0][3] + bv0);
      *(uint2*)&W[VO + l15 * 72 + mt * 16 + 4 * l4] = u;
      u.x = pack2(aV[mt][1][0] + bv1, aV[mt][1][1] + bv1);
      u.y = pack2(aV[mt][1][2] + bv1, aV[mt][1][3] + bv1);
      *(uint2*)&W[VO + (16 + l15) * 72 + mt * 16 + 4 * l4] = u;
    }
  }

  // ---- QK^T (S^T layout: lane holds row i = mt*16+l15, cols j = nt*16+4*l4+r) ----
  f32x4 s[4][4];
#pragma unroll
  for (int mt = 0; mt < 4; ++mt)
#pragma unroll
    for (int nt = 0; nt < 4; ++nt) s[mt][nt] = z4;
  {
    short8 qf[4], kf[4];
#pragma unroll
    for (int mt = 0; mt < 4; ++mt)
      qf[mt] = *(const short8*)&W[QO + (mt * 16 + l15) * 40 + l4 * 8];
#pragma unroll
    for (int nt = 0; nt < 4; ++nt)
      kf[nt] = *(const short8*)&W[KO + (nt * 16 + l15) * 40 + l4 * 8];
#pragma unroll
    for (int mt = 0; mt < 4; ++mt)
#pragma unroll
      for (int nt = 0; nt < 4; ++nt)
        s[mt][nt] = __builtin_amdgcn_mfma_f32_16x16x32_bf16(kf[nt], qf[mt], s[mt][nt], 0, 0, 0);
  }

  // ---- softmax with max-sub + exact-zero masking (known-good numerics) ----
  int ih4[4], iw4[4], irg[4];
#pragma unroll
  for (int mt = 0; mt < 4; ++mt) {
    const int i = mt * 16 + l15;
    const int ihh = i / 7, iww = i - ihh * 7;
    ih4[mt] = ihh; iw4[mt] = iww;
    irg[mt] = 3 * reg3(wh * 7 + ihh) + reg3(ww * 7 + iww);
  }
  float pmax[4] = {-1e30f, -1e30f, -1e30f, -1e30f};
#pragma unroll
  for (int nt = 0; nt < 4; ++nt) {
#pragma unroll
    for (int r = 0; r < 4; ++r) {
      const int j = nt * 16 + 4 * l4 + r;
      const int jhh = j / 7, jww = j - jhh * 7;
      const int jrg = 3 * reg3(wh * 7 + jhh) + reg3(ww * 7 + jww);
      const bool jbad = (j >= 49);
#pragma unroll
      for (int mt = 0; mt < 4; ++mt) {
        int didx = (ih4[mt] - jhh + 6) * 13 + (iw4[mt] - jww + 6);
        didx = didx < 0 ? 0 : (didx > 168 ? 168 : didx);
        float v = s[mt][nt][r] + tblw[didx];
        if (irg[mt] != jrg) v -= 100.0f;
        if (jbad) v = -1e30f;
        s[mt][nt][r] = v;
        pmax[mt] = fmaxf(pmax[mt], v);
      }
    }
  }
  float inv[4];
#pragma unroll
  for (int mt = 0; mt < 4; ++mt) {
    float m0 = pmax[mt];
    m0 = fmaxf(m0, __shfl_xor(m0, 16));
    m0 = fmaxf(m0, __shfl_xor(m0, 32));
    float sum = 0.0f;
#pragma unroll
    for (int nt = 0; nt < 4; ++nt)
#pragma unroll
      for (int r = 0; r < 4; ++r) {
        const float v = s[mt][nt][r];
        const float e = (v > -1e29f) ? __expf(v - m0) : 0.0f;
        s[mt][nt][r] = e;
        sum += e;
      }
    sum += __shfl_xor(sum, 16);
    sum += __shfl_xor(sum, 32);
    inv[mt] = 1.0f / sum;
  }

  // ---- P pass 0 (j in [0,32)) -> PV pass 0 -> P pass 1 -> PV pass 1 ----
  f32x4 o[4][2];
#pragma unroll
  for (int mt = 0; mt < 4; ++mt)
#pragma unroll
    for (int dt = 0; dt < 2; ++dt) o[mt][dt] = z4;
#pragma unroll
  for (int mt = 0; mt < 4; ++mt) {
    const int i = mt * 16 + l15;
    if (i < 49) {
#pragma unroll
      for (int nt = 0; nt < 2; ++nt) {
        uint2 u;
        u.x = pack2(s[mt][nt][0] * inv[mt], s[mt][nt][1] * inv[mt]);
        u.y = pack2(s[mt][nt][2] * inv[mt], s[mt][nt][3] * inv[mt]);
        *(uint2*)&W[QO + i * 40 + nt * 16 + 4 * l4] = u;
      }
    }
  }
  {
    short8 pa[4], vb[2];
#pragma unroll
    for (int mt = 0; mt < 4; ++mt)
      pa[mt] = *(const short8*)&W[QO + (mt * 16 + l15) * 40 + l4 * 8];
#pragma unroll
    for (int dt = 0; dt < 2; ++dt)
      vb[dt] = *(const short8*)&W[VO + (dt * 16 + l15) * 72 + l4 * 8];
#pragma unroll
    for (int mt = 0; mt < 4; ++mt)
#pragma unroll
      for (int dt = 0; dt < 2; ++dt)
        o[mt][dt] = __builtin_amdgcn_mfma_f32_16x16x32_bf16(vb[dt], pa[mt], o[mt][dt], 0, 0, 0);
  }
#pragma unroll
  for (int mt = 0; mt < 4; ++mt) {
    const int i = mt * 16 + l15;
    if (i < 49) {
#pragma unroll
      for (int nt = 2; nt < 4; ++nt) {
        uint2 u;
        u.x = pack2(s[mt][nt][0] * inv[mt], s[mt][nt][1] * inv[mt]);
        u.y = pack2(s[mt][nt][2] * inv[mt], s[mt][nt][3] * inv[mt]);
        *(uint2*)&W[QO + i * 40 + (nt - 2) * 16 + 4 * l4] = u;
      }
    }
  }
  {
    short8 pa[4], vb[2];
#pragma unroll
    for (int mt = 0; mt < 4; ++mt)
      pa[mt] = *(const short8*)&W[QO + (mt * 16 + l15) * 40 + l4 * 8];
#pragma unroll
    for (int dt = 0; dt < 2; ++dt)
      vb[dt] = *(const short8*)&W[VO + (dt * 16 + l15) * 72 + 32 + l4 * 8];
#pragma unroll
    for (int mt = 0; mt < 4; ++mt)
#pragma unroll
      for (int dt = 0; dt < 2; ++dt)
        o[mt][dt] = __builtin_amdgcn_mfma_f32_16x16x32_bf16(vb[dt], pa[mt], o[mt][dt], 0, 0, 0);
  }
  // stage O (lane: t=l15-row, 4 consecutive d) -> K buffer [t][40]
#pragma unroll
  for (int mt = 0; mt < 4; ++mt) {
    const int t = mt * 16 + l15;
#pragma unroll
    for (int dt = 0; dt < 2; ++dt) {
      uint2 u;
      u.x = pack2(o[mt][dt][0], o[mt][dt][1]);
      u.y = pack2(o[mt][dt][2], o[mt][dt][3]);
      *(uint2*)&W[KO + t * 40 + dt * 16 + 4 * l4] = u;
    }
  }
  __syncthreads();

  // ---- proj (swapped): lane holds t=l15-row, 4 consecutive n ----
  const float4 pbv0 = *(const float4*)(pb + wv * 32 + 4 * l4);
  const float4 pbv1 = *(const float4*)(pb + wv * 32 + 16 + 4 * l4);
  f32x4 c2[4][2];
#pragma unroll
  for (int mt = 0; mt < 4; ++mt)
#pragma unroll
    for (int nt = 0; nt < 2; ++nt) c2[mt][nt] = z4;
#pragma unroll
  for (int ks = 0; ks < 4; ++ks) {
    short8 a2[4], bp[2];
#pragma unroll
    for (int mt = 0; mt < 4; ++mt)
      a2[mt] = *(const short8*)&lds[ks * WSTRIDE + KO + (mt * 16 + l15) * 40 + l4 * 8];
#pragma unroll
    for (int nt = 0; nt < 2; ++nt)
      bp[nt] = *(const short8*)&Wp[(size_t)(wv * 32 + nt * 16 + l15) * 128 + ks * 32 + l4 * 8];
#pragma unroll
    for (int mt = 0; mt < 4; ++mt)
#pragma unroll
      for (int nt = 0; nt < 2; ++nt)
        c2[mt][nt] = __builtin_amdgcn_mfma_f32_16x16x32_bf16(bp[nt], a2[mt], c2[mt][nt], 0, 0, 0);
  }
#pragma unroll
  for (int mt = 0; mt < 4; ++mt) {
    const int t = mt * 16 + l15;
    if (t < 49) {
      const int th = t / 7, tw = t - th * 7;
      int y = wh * 7 + th + 3; if (y >= 56) y -= 56;
      int xx = ww * 7 + tw + 3; if (xx >= 56) xx -= 56;
      float* dstp = out + (((size_t)(b * 56 + y)) * 56 + xx) * 128 + wv * 32 + 4 * l4;
      float4 v0, v1;
      v0.x = c2[mt][0][0] + pbv0.x; v0.y = c2[mt][0][1] + pbv0.y;
      v0.z = c2[mt][0][2] + pbv0.z; v0.w = c2[mt][0][3] + pbv0.w;
      *(float4*)(dstp) = v0;
      v1.x = c2[mt][1][0] + pbv1.x; v1.y = c2[mt][1][1] + pbv1.y;
      v1.z = c2[mt][1][2] + pbv1.z; v1.w = c2[mt][1][3] + pbv1.w;
      *(float4*)(dstp + 16) = v1;
    }
  }
}

extern "C" void kernel_launch(void* const* d_in, const int* in_sizes, int n_in,
                              void* d_out, int out_size, void* d_ws, size_t ws_size,
                              hipStream_t stream) {
  const float* x     = (const float*)d_in[0];
  const float* qkvw  = (const float*)d_in[1];
  const float* qkvb  = (const float*)d_in[2];
  const float* projw = (const float*)d_in[3];
  const float* projb = (const float*)d_in[4];
  const float* table = (const float*)d_in[5];
  float* out = (float*)d_out;
  char* ws = (char*)d_ws;
  unsigned short* Wq = (unsigned short*)ws;            // 98304 B
  unsigned short* Wp = (unsigned short*)(ws + 98304);  // 32768 B

  k_prep<<<dim3(192), dim3(256), 0, stream>>>(qkvw, projw, Wq, Wp);
  k_fused<<<dim3(4096), dim3(256), 0, stream>>>(x, Wq, qkvb, Wp, projb, table, out);
}